// Round 2
// baseline (3967.933 us; speedup 1.0000x reference)
//
#include <hip/hip_runtime.h>
#include <stdint.h>

typedef unsigned int uint32;
typedef __bf16 bf16x8 __attribute__((ext_vector_type(8)));
typedef float floatx4 __attribute__((ext_vector_type(4)));

#define LROW 68  // words per staged row (64 data + 4 pad)
#define MFMA16(a,b,c) __builtin_amdgcn_mfma_f32_16x16x32_bf16(a,b,c,0,0,0)

__device__ __forceinline__ uint32 pack_bf16(float lo, float hi) {
  uint32 a = __builtin_bit_cast(uint32, lo);
  uint32 b = __builtin_bit_cast(uint32, hi);
  return ((b + 0x8000u) & 0xffff0000u) | ((a + 0x8000u) >> 16);
}
__device__ __forceinline__ float bf_lo(uint32 u) { return __builtin_bit_cast(float, u << 16); }
__device__ __forceinline__ float bf_hi(uint32 u) { return __builtin_bit_cast(float, u & 0xffff0000u); }
__device__ __forceinline__ float bcast(float v, int l) {
  return __builtin_bit_cast(float, __builtin_amdgcn_readlane(__builtin_bit_cast(int, v), l));
}

// ws layout (uint32 words):
// [0,4096)        A0   : w0 A-frags, RB=8, KS=2        (M=128,K=64)
// [4096,16384)    A23  : [-w2;w3;w1] A-frags RB=12 KS=4 (M=192,K=128)
// [16384,17408)   AP1  : pw1 A-frags RB=4 KS=1 (K padded 8->32)
// [17408,19456)   AP2  : pw2 A-frags RB=4 KS=2 (M=64,K=64)
// [19456,23552)   CW1  : [(rb*4+r)][lane][j2] packed bf16 pairs
// [23552,27648)   WO   : [cg][lane][cl] pack(wout[lane][c], wout[lane+64][c])
// [27648,28160)   CW2  : [lane][j] pack(cw2[lane][j], cw2[lane+64][j])
// [28160,31232)   BIN  : fp32 [rb<12][lane][r]  (-b2 / b3 / b1)
// [31232,33280)   B0N  : fp32 [rb<8][lane][r]   (b0)
__global__ void pack_w(const float* __restrict__ w0, const float* __restrict__ w1,
                       const float* __restrict__ w2, const float* __restrict__ w3,
                       const float* __restrict__ pw1, const float* __restrict__ pw2,
                       const float* __restrict__ cw1, const float* __restrict__ cw2,
                       const float* __restrict__ b0, const float* __restrict__ b1,
                       const float* __restrict__ b2, const float* __restrict__ b3,
                       const float* __restrict__ wout, uint32* __restrict__ ws) {
  int t = threadIdx.x + blockIdx.x * blockDim.x;
  int st = blockDim.x * gridDim.x;
  for (int i = t; i < 4096; i += st) {  // A0
    int w = i & 3, lane = (i >> 2) & 63, fi = i >> 8;
    int rb = fi >> 1, ks = fi & 1;
    int m = rb * 16 + (lane & 15), k0 = ks * 32 + ((lane >> 4) & 3) * 8 + 2 * w;
    ws[i] = pack_bf16(w0[m * 64 + k0], w0[m * 64 + k0 + 1]);
  }
  for (int i = t; i < 12288; i += st) {  // A23
    int w = i & 3, lane = (i >> 2) & 63, fi = i >> 8;
    int rb = fi >> 2, ks = fi & 3;
    int m = rb * 16 + (lane & 15), k0 = ks * 32 + ((lane >> 4) & 3) * 8 + 2 * w;
    float v0, v1;
    if (m < 64)       { v0 = -w2[m * 128 + k0];          v1 = -w2[m * 128 + k0 + 1]; }
    else if (m < 128) { v0 =  w3[(m - 64) * 128 + k0];   v1 =  w3[(m - 64) * 128 + k0 + 1]; }
    else              { v0 =  w1[(m - 128) * 128 + k0];  v1 =  w1[(m - 128) * 128 + k0 + 1]; }
    ws[4096 + i] = pack_bf16(v0, v1);
  }
  for (int i = t; i < 1024; i += st) {  // AP1 (K padded to 32)
    int w = i & 3, lane = (i >> 2) & 63, rb = i >> 8;
    int m = rb * 16 + (lane & 15), k0 = ((lane >> 4) & 3) * 8 + 2 * w;
    float v0 = (k0 < 8) ? pw1[m * 8 + k0] : 0.f;
    float v1 = (k0 + 1 < 8) ? pw1[m * 8 + k0 + 1] : 0.f;
    ws[16384 + i] = pack_bf16(v0, v1);
  }
  for (int i = t; i < 2048; i += st) {  // AP2
    int w = i & 3, lane = (i >> 2) & 63, fi = i >> 8;
    int rb = fi >> 1, ks = fi & 1;
    int m = rb * 16 + (lane & 15), k0 = ks * 32 + ((lane >> 4) & 3) * 8 + 2 * w;
    ws[17408 + i] = pack_bf16(pw2[m * 64 + k0], pw2[m * 64 + k0 + 1]);
  }
  for (int i = t; i < 4096; i += st) {  // CW1
    int j2 = i & 3, lane = (i >> 2) & 63, rr = i >> 8;
    int rb = rr >> 2, r = rr & 3;
    int c = rb * 16 + ((lane >> 4) & 3) * 4 + r, kk = lane & 15;
    ws[19456 + i] = pack_bf16(cw1[j2 * 1024 + c * 16 + kk], cw1[(j2 + 4) * 1024 + c * 16 + kk]);
  }
  for (int i = t; i < 4096; i += st) {  // WO
    int cl = i & 3, lane = (i >> 2) & 63, cg = i >> 8;
    int c = cg * 4 + cl;
    ws[23552 + i] = pack_bf16(wout[lane * 64 + c], wout[(lane + 64) * 64 + c]);
  }
  for (int i = t; i < 512; i += st) {  // CW2
    int j = i & 7, lane = i >> 3;
    ws[27648 + i] = pack_bf16(cw2[lane * 8 + j], cw2[(lane + 64) * 8 + j]);
  }
  float* wsf = (float*)ws;
  for (int i = t; i < 3072; i += st) {  // BIN
    int r = i & 3, lane = (i >> 2) & 63, rb = i >> 8;
    int c = (rb & 3) * 16 + ((lane >> 4) & 3) * 4 + r;
    wsf[28160 + i] = (rb < 4) ? -b2[c] : (rb < 8 ? b3[c] : b1[c]);
  }
  for (int i = t; i < 2048; i += st) {  // B0N
    int r = i & 3, lane = (i >> 2) & 63, rb = i >> 8;
    int c = rb * 16 + ((lane >> 4) & 3) * 4 + r;
    wsf[31232 + i] = b0[c];
  }
}

__launch_bounds__(256, 3)
__global__ void pt_mfma(const float* __restrict__ feats, const float* __restrict__ ppfs,
                        const float* __restrict__ cb2, const float* __restrict__ bout,
                        const uint32* __restrict__ ws, float* __restrict__ out) {
  __shared__ __align__(16) uint32 lds[4 * 48 * LROW];
  const int tid = threadIdx.x, lane = tid & 63, wv = tid >> 6;
  const int q = lane >> 4, nn = lane & 15;
  uint32* xnbuf = lds + wv * 48 * LROW;   // 32 rows (16 g8-groups x 2 cb)
  uint32* tbuf = xnbuf + 32 * LROW;       // 16 rows

  const uint4* A0  = (const uint4*)ws;
  const uint4* A23 = (const uint4*)(ws + 4096);
  const uint4* AP1 = (const uint4*)(ws + 16384);
  const uint4* AP2 = (const uint4*)(ws + 17408);
  const uint4* CW1 = (const uint4*)(ws + 19456);
  const uint4* WO  = (const uint4*)(ws + 23552);
  const uint4* CW2 = (const uint4*)(ws + 27648);
  const uint4* BIN = (const uint4*)(ws + 28160);
  const uint4* B0N = (const uint4*)(ws + 31232);

  const float cb2A = cb2[lane], cb2B = cb2[lane + 64];
  const float boutA = bout[lane], boutB = bout[lane + 64];
  const int gwave = blockIdx.x * 4 + wv;

  for (int it = 0; it < 8; ++it) {
    const int tile = it * 4096 + gwave;
    const int p0 = tile * 2;
    const int b = p0 >> 14, n0 = p0 & 16383;  // both cb positions share b (n0 even)

    // ---- feats B-frags (cb, ks): B[k=c][n=kk]
    bf16x8 bft[2][2];
#pragma unroll
    for (int cb = 0; cb < 2; cb++) {
      const float* fb = feats + (((size_t)b * 64) * 16384 + (n0 + cb)) * 16 + nn;
#pragma unroll
      for (int ks = 0; ks < 2; ks++) {
        float fv[8];
#pragma unroll
        for (int j = 0; j < 8; j++) { int c = ks * 32 + q * 8 + j; fv[j] = fb[(size_t)c * 262144]; }
        uint4 u;
        u.x = pack_bf16(fv[0], fv[1]); u.y = pack_bf16(fv[2], fv[3]);
        u.z = pack_bf16(fv[4], fv[5]); u.w = pack_bf16(fv[6], fv[7]);
        bft[cb][ks] = __builtin_bit_cast(bf16x8, u);
      }
    }
    // ---- GEMM1: xn = relu(w0@feats + b0)
    floatx4 acc1[8][2];
#pragma unroll
    for (int rb = 0; rb < 8; rb++) {
      floatx4 bi = __builtin_bit_cast(floatx4, B0N[rb * 64 + lane]);
      acc1[rb][0] = bi; acc1[rb][1] = bi;
    }
#pragma unroll
    for (int rb = 0; rb < 8; rb++)
#pragma unroll
      for (int ks = 0; ks < 2; ks++) {
        bf16x8 a = __builtin_bit_cast(bf16x8, A0[(rb * 2 + ks) * 64 + lane]);
        acc1[rb][0] = MFMA16(a, bft[0][ks], acc1[rb][0]);
        acc1[rb][1] = MFMA16(a, bft[1][ks], acc1[rb][1]);
      }
    // relu + store xn to LDS in B-frag layout
#pragma unroll
    for (int rb = 0; rb < 8; rb++)
#pragma unroll
      for (int cb = 0; cb < 2; cb++) {
        float v0 = fmaxf(acc1[rb][cb][0], 0.f), v1 = fmaxf(acc1[rb][cb][1], 0.f);
        float v2 = fmaxf(acc1[rb][cb][2], 0.f), v3 = fmaxf(acc1[rb][cb][3], 0.f);
        int g8 = 2 * rb + (q >> 1);
        int base = (g8 * 2 + cb) * LROW + nn * 4 + (q & 1) * 2;
        xnbuf[base] = pack_bf16(v0, v1); xnbuf[base + 1] = pack_bf16(v2, v3);
      }
    // ---- pw1: t = relu(pw1 @ ppfs)
    bf16x8 bpp[2];
#pragma unroll
    for (int cb = 0; cb < 2; cb++) {
      uint4 u;
      if (q == 0) {
        const float* pb = ppfs + (((size_t)b * 8) * 16384 + (n0 + cb)) * 16 + nn;
        float pv[8];
#pragma unroll
        for (int j = 0; j < 8; j++) pv[j] = pb[(size_t)j * 262144];
        u.x = pack_bf16(pv[0], pv[1]); u.y = pack_bf16(pv[2], pv[3]);
        u.z = pack_bf16(pv[4], pv[5]); u.w = pack_bf16(pv[6], pv[7]);
      } else { u.x = 0u; u.y = 0u; u.z = 0u; u.w = 0u; }
      bpp[cb] = __builtin_bit_cast(bf16x8, u);
    }
    floatx4 acct[4][2];
#pragma unroll
    for (int rb = 0; rb < 4; rb++) {
      floatx4 z = {0.f, 0.f, 0.f, 0.f};
      acct[rb][0] = z; acct[rb][1] = z;
    }
#pragma unroll
    for (int rb = 0; rb < 4; rb++) {
      bf16x8 a = __builtin_bit_cast(bf16x8, AP1[rb * 64 + lane]);
      acct[rb][0] = MFMA16(a, bpp[0], acct[rb][0]);
      acct[rb][1] = MFMA16(a, bpp[1], acct[rb][1]);
    }
#pragma unroll
    for (int rb = 0; rb < 4; rb++)
#pragma unroll
      for (int cb = 0; cb < 2; cb++) {
        float v0 = fmaxf(acct[rb][cb][0], 0.f), v1 = fmaxf(acct[rb][cb][1], 0.f);
        float v2 = fmaxf(acct[rb][cb][2], 0.f), v3 = fmaxf(acct[rb][cb][3], 0.f);
        int g8 = 2 * rb + (q >> 1);
        int base = (g8 * 2 + cb) * LROW + nn * 4 + (q & 1) * 2;
        tbuf[base] = pack_bf16(v0, v1); tbuf[base + 1] = pack_bf16(v2, v3);
      }
    // ---- GEMM2 (rows 0-63: ptf-x2-b2, 64-127: x3+ptf+b3, 128-191: x1+b1)
    floatx4 acc2[12][2];
#pragma unroll
    for (int rb = 0; rb < 12; rb++) {
      floatx4 bi = __builtin_bit_cast(floatx4, BIN[rb * 64 + lane]);
      acc2[rb][0] = bi; acc2[rb][1] = bi;
    }
#pragma unroll
    for (int ks = 0; ks < 2; ks++) {  // pw2 @ t  (K=64)
      bf16x8 bt0 = __builtin_bit_cast(bf16x8, *(const uint4*)(tbuf + ((ks * 4 + q) * 2 + 0) * LROW + nn * 4));
      bf16x8 bt1 = __builtin_bit_cast(bf16x8, *(const uint4*)(tbuf + ((ks * 4 + q) * 2 + 1) * LROW + nn * 4));
#pragma unroll
      for (int rbq = 0; rbq < 4; rbq++) {
        bf16x8 a = __builtin_bit_cast(bf16x8, AP2[(rbq * 2 + ks) * 64 + lane]);
        acc2[rbq][0] = MFMA16(a, bt0, acc2[rbq][0]);
        acc2[rbq][1] = MFMA16(a, bt1, acc2[rbq][1]);
        acc2[rbq + 4][0] = MFMA16(a, bt0, acc2[rbq + 4][0]);
        acc2[rbq + 4][1] = MFMA16(a, bt1, acc2[rbq + 4][1]);
      }
    }
#pragma unroll
    for (int ks = 0; ks < 4; ks++) {  // [-w2;w3;w1] @ xn  (K=128)
      bf16x8 bx0 = __builtin_bit_cast(bf16x8, *(const uint4*)(xnbuf + ((ks * 4 + q) * 2 + 0) * LROW + nn * 4));
      bf16x8 bx1 = __builtin_bit_cast(bf16x8, *(const uint4*)(xnbuf + ((ks * 4 + q) * 2 + 1) * LROW + nn * 4));
#pragma unroll
      for (int rb = 0; rb < 12; rb++) {
        bf16x8 a = __builtin_bit_cast(bf16x8, A23[(rb * 4 + ks) * 64 + lane]);
        acc2[rb][0] = MFMA16(a, bx0, acc2[rb][0]);
        acc2[rb][1] = MFMA16(a, bx1, acc2[rb][1]);
      }
    }
    // ---- epilogue per position
#pragma unroll
    for (int cb = 0; cb < 2; cb++) {
      // Phase F: h = relu(cw1 . xfs), xfs = x1 + (ptf - x2)
      float hp[8] = {0.f, 0.f, 0.f, 0.f, 0.f, 0.f, 0.f, 0.f};
#pragma unroll
      for (int rb = 0; rb < 4; rb++)
#pragma unroll
        for (int r = 0; r < 4; r++) {
          float xfs = __shfl(acc2[8 + rb][cb][r], lane & 0x30, 64) + acc2[rb][cb][r];
          uint4 u = CW1[(rb * 4 + r) * 64 + lane];
          hp[0] = fmaf(bf_lo(u.x), xfs, hp[0]); hp[4] = fmaf(bf_hi(u.x), xfs, hp[4]);
          hp[1] = fmaf(bf_lo(u.y), xfs, hp[1]); hp[5] = fmaf(bf_hi(u.y), xfs, hp[5]);
          hp[2] = fmaf(bf_lo(u.z), xfs, hp[2]); hp[6] = fmaf(bf_hi(u.z), xfs, hp[6]);
          hp[3] = fmaf(bf_lo(u.w), xfs, hp[3]); hp[7] = fmaf(bf_hi(u.w), xfs, hp[7]);
        }
      float h[8];
#pragma unroll
      for (int j = 0; j < 8; j++) {
        float v = hp[j];
        v += __shfl_xor(v, 1, 64); v += __shfl_xor(v, 2, 64); v += __shfl_xor(v, 4, 64);
        v += __shfl_xor(v, 8, 64); v += __shfl_xor(v, 16, 64); v += __shfl_xor(v, 32, 64);
        h[j] = fmaxf(v, 0.f);
      }
      // Phase G: wl = cb2 + cw2 @ h
      float wlA = cb2A, wlB = cb2B;
      {
        uint4 c0 = CW2[lane * 2], c1 = CW2[lane * 2 + 1];
        wlA = fmaf(bf_lo(c0.x), h[0], wlA); wlB = fmaf(bf_hi(c0.x), h[0], wlB);
        wlA = fmaf(bf_lo(c0.y), h[1], wlA); wlB = fmaf(bf_hi(c0.y), h[1], wlB);
        wlA = fmaf(bf_lo(c0.z), h[2], wlA); wlB = fmaf(bf_hi(c0.z), h[2], wlB);
        wlA = fmaf(bf_lo(c0.w), h[3], wlA); wlB = fmaf(bf_hi(c0.w), h[3], wlB);
        wlA = fmaf(bf_lo(c1.x), h[4], wlA); wlB = fmaf(bf_hi(c1.x), h[4], wlB);
        wlA = fmaf(bf_lo(c1.y), h[5], wlA); wlB = fmaf(bf_hi(c1.y), h[5], wlB);
        wlA = fmaf(bf_lo(c1.z), h[6], wlA); wlB = fmaf(bf_hi(c1.z), h[6], wlB);
        wlA = fmaf(bf_lo(c1.w), h[7], wlA); wlB = fmaf(bf_hi(c1.w), h[7], wlB);
      }
      // Phase H: softmax over k within 16-lane groups
      float mA = wlA, mB = wlB;
#pragma unroll
      for (int s = 1; s < 16; s <<= 1) {
        mA = fmaxf(mA, __shfl_xor(mA, s, 64));
        mB = fmaxf(mB, __shfl_xor(mB, s, 64));
      }
      float eA = __expf(wlA - mA), eB = __expf(wlB - mB);
      float sA = eA, sB = eB;
#pragma unroll
      for (int s = 1; s < 16; s <<= 1) {
        sA += __shfl_xor(sA, s, 64);
        sB += __shfl_xor(sB, s, 64);
      }
      float smAv = eA / sA, smBv = eB / sB;
      // Phase I: om[c] = relu(sum_k sm[c%8][k] * x3p[c][k])
      float sma[4], smb[4];
#pragma unroll
      for (int r = 0; r < 4; r++) {
        int src = r * 16 + nn;
        sma[r] = __shfl(smAv, src, 64);
        smb[r] = __shfl(smBv, src, 64);
      }
      const bool qodd = (q & 1);
      float om[4][4];
#pragma unroll
      for (int rb = 0; rb < 4; rb++)
#pragma unroll
        for (int r = 0; r < 4; r++) {
          float sv = qodd ? smb[r] : sma[r];
          float v = sv * acc2[4 + rb][cb][r];
          v += __shfl_xor(v, 1, 64); v += __shfl_xor(v, 2, 64);
          v += __shfl_xor(v, 4, 64); v += __shfl_xor(v, 8, 64);
          om[rb][r] = fmaxf(v, 0.f);
        }
      // Phase J: out = wout @ om + bout + identity
      float outA = boutA, outB = boutB;
#pragma unroll
      for (int cg = 0; cg < 16; cg++) {
        uint4 u = WO[cg * 64 + lane];
        int rb = cg >> 2, qq = (cg & 3) * 16;
        float s0 = bcast(om[rb][0], qq), s1 = bcast(om[rb][1], qq);
        float s2 = bcast(om[rb][2], qq), s3 = bcast(om[rb][3], qq);
        outA = fmaf(bf_lo(u.x), s0, outA); outB = fmaf(bf_hi(u.x), s0, outB);
        outA = fmaf(bf_lo(u.y), s1, outA); outB = fmaf(bf_hi(u.y), s1, outB);
        outA = fmaf(bf_lo(u.z), s2, outA); outB = fmaf(bf_hi(u.z), s2, outB);
        outA = fmaf(bf_lo(u.w), s3, outA); outB = fmaf(bf_hi(u.w), s3, outB);
      }
      // identity (xn col 0, bf16 from LDS)
      {
        int g8a = lane >> 3, wo = (lane & 7) >> 1;
        uint32 ia = xnbuf[(g8a * 2 + cb) * LROW + wo];
        uint32 ib = xnbuf[((8 + g8a) * 2 + cb) * LROW + wo];
        outA += (lane & 1) ? bf_hi(ia) : bf_lo(ia);
        outB += (lane & 1) ? bf_hi(ib) : bf_lo(ib);
      }
      const int npos = n0 + cb;
      out[((size_t)(b * 128 + lane)) * 16384 + npos] = outA;
      out[((size_t)(b * 128 + lane + 64)) * 16384 + npos] = outB;
    }
  }
}

extern "C" void kernel_launch(void* const* d_in, const int* in_sizes, int n_in,
                              void* d_out, int out_size, void* d_ws, size_t ws_size,
                              hipStream_t stream) {
  const float* feats = (const float*)d_in[0];
  const float* ppfs = (const float*)d_in[1];
  const float* w0 = (const float*)d_in[2];
  const float* b0 = (const float*)d_in[3];
  const float* w1 = (const float*)d_in[4];
  const float* b1 = (const float*)d_in[5];
  const float* w2 = (const float*)d_in[6];
  const float* b2 = (const float*)d_in[7];
  const float* w3 = (const float*)d_in[8];
  const float* b3 = (const float*)d_in[9];
  const float* pw1 = (const float*)d_in[10];
  const float* pw2 = (const float*)d_in[11];
  const float* cw1 = (const float*)d_in[12];
  const float* cw2 = (const float*)d_in[13];
  const float* cb2 = (const float*)d_in[14];
  const float* wout = (const float*)d_in[15];
  const float* bout = (const float*)d_in[16];
  (void)in_sizes; (void)n_in; (void)out_size; (void)ws_size;

  uint32* ws = (uint32*)d_ws;
  hipLaunchKernelGGL(pack_w, dim3(40), dim3(256), 0, stream,
                     w0, w1, w2, w3, pw1, pw2, cw1, cw2, b0, b1, b2, b3, wout, ws);
  hipLaunchKernelGGL(pt_mfma, dim3(1024), dim3(256), 0, stream,
                     feats, ppfs, cb2, bout, ws, (float*)d_out);
}

// Round 3
// 3759.739 us; speedup vs baseline: 1.0554x; 1.0554x over previous
//
#include <hip/hip_runtime.h>
#include <stdint.h>

typedef unsigned int uint32;
typedef __bf16 bf16x8 __attribute__((ext_vector_type(8)));
typedef float floatx4 __attribute__((ext_vector_type(4)));

#define LROW 68  // words per staged row (64 data + 4 pad)
#define MFMA16(a,b,c) __builtin_amdgcn_mfma_f32_16x16x32_bf16(a,b,c,0,0,0)

__device__ __forceinline__ uint32 pack_bf16(float lo, float hi) {
  uint32 a = __builtin_bit_cast(uint32, lo);
  uint32 b = __builtin_bit_cast(uint32, hi);
  return ((b + 0x8000u) & 0xffff0000u) | ((a + 0x8000u) >> 16);
}
__device__ __forceinline__ float bf_lo(uint32 u) { return __builtin_bit_cast(float, u << 16); }
__device__ __forceinline__ float bf_hi(uint32 u) { return __builtin_bit_cast(float, u & 0xffff0000u); }
__device__ __forceinline__ float bcast(float v, int l) {
  return __builtin_bit_cast(float, __builtin_amdgcn_readlane(__builtin_bit_cast(int, v), l));
}

// ws layout (uint32 words):
// [0,4096)        A0   : w0 A-frags, RB=8, KS=2        (M=128,K=64)
// [4096,16384)    A23  : [-w2;w3;w1] A-frags RB=12 KS=4 (M=192,K=128)
// [16384,17408)   AP1  : pw1 A-frags RB=4 KS=1 (K padded 8->32)
// [17408,19456)   AP2  : pw2 A-frags RB=4 KS=2 (M=64,K=64)
// [19456,23552)   CW1  : [(rb*4+r)][lane][j2] packed bf16 pairs
// [23552,27648)   WO   : [cg][lane][cl] pack(wout[lane][c], wout[lane+64][c])
// [27648,28160)   CW2  : [lane][j] pack(cw2[lane][j], cw2[lane+64][j])
__global__ void pack_w(const float* __restrict__ w0, const float* __restrict__ w1,
                       const float* __restrict__ w2, const float* __restrict__ w3,
                       const float* __restrict__ pw1, const float* __restrict__ pw2,
                       const float* __restrict__ cw1, const float* __restrict__ cw2,
                       const float* __restrict__ wout, uint32* __restrict__ ws) {
  int t = threadIdx.x + blockIdx.x * blockDim.x;
  int st = blockDim.x * gridDim.x;
  for (int i = t; i < 4096; i += st) {  // A0
    int w = i & 3, lane = (i >> 2) & 63, fi = i >> 8;
    int rb = fi >> 1, ks = fi & 1;
    int m = rb * 16 + (lane & 15), k0 = ks * 32 + ((lane >> 4) & 3) * 8 + 2 * w;
    ws[i] = pack_bf16(w0[m * 64 + k0], w0[m * 64 + k0 + 1]);
  }
  for (int i = t; i < 12288; i += st) {  // A23
    int w = i & 3, lane = (i >> 2) & 63, fi = i >> 8;
    int rb = fi >> 2, ks = fi & 3;
    int m = rb * 16 + (lane & 15), k0 = ks * 32 + ((lane >> 4) & 3) * 8 + 2 * w;
    float v0, v1;
    if (m < 64)       { v0 = -w2[m * 128 + k0];          v1 = -w2[m * 128 + k0 + 1]; }
    else if (m < 128) { v0 =  w3[(m - 64) * 128 + k0];   v1 =  w3[(m - 64) * 128 + k0 + 1]; }
    else              { v0 =  w1[(m - 128) * 128 + k0];  v1 =  w1[(m - 128) * 128 + k0 + 1]; }
    ws[4096 + i] = pack_bf16(v0, v1);
  }
  for (int i = t; i < 1024; i += st) {  // AP1 (K padded to 32)
    int w = i & 3, lane = (i >> 2) & 63, rb = i >> 8;
    int m = rb * 16 + (lane & 15), k0 = ((lane >> 4) & 3) * 8 + 2 * w;
    float v0 = (k0 < 8) ? pw1[m * 8 + k0] : 0.f;
    float v1 = (k0 + 1 < 8) ? pw1[m * 8 + k0 + 1] : 0.f;
    ws[16384 + i] = pack_bf16(v0, v1);
  }
  for (int i = t; i < 2048; i += st) {  // AP2
    int w = i & 3, lane = (i >> 2) & 63, fi = i >> 8;
    int rb = fi >> 1, ks = fi & 1;
    int m = rb * 16 + (lane & 15), k0 = ks * 32 + ((lane >> 4) & 3) * 8 + 2 * w;
    ws[17408 + i] = pack_bf16(pw2[m * 64 + k0], pw2[m * 64 + k0 + 1]);
  }
  for (int i = t; i < 4096; i += st) {  // CW1
    int j2 = i & 3, lane = (i >> 2) & 63, rr = i >> 8;
    int rb = rr >> 2, r = rr & 3;
    int c = rb * 16 + ((lane >> 4) & 3) * 4 + r, kk = lane & 15;
    ws[19456 + i] = pack_bf16(cw1[j2 * 1024 + c * 16 + kk], cw1[(j2 + 4) * 1024 + c * 16 + kk]);
  }
  for (int i = t; i < 4096; i += st) {  // WO
    int cl = i & 3, lane = (i >> 2) & 63, cg = i >> 8;
    int c = cg * 4 + cl;
    ws[23552 + i] = pack_bf16(wout[lane * 64 + c], wout[(lane + 64) * 64 + c]);
  }
  for (int i = t; i < 512; i += st) {  // CW2
    int j = i & 7, lane = i >> 3;
    ws[27648 + i] = pack_bf16(cw2[lane * 8 + j], cw2[(lane + 64) * 8 + j]);
  }
}

__launch_bounds__(256, 3)
__global__ void pt_mfma(const float* __restrict__ feats, const float* __restrict__ ppfs,
                        const float* __restrict__ b0, const float* __restrict__ b1,
                        const float* __restrict__ b2, const float* __restrict__ b3,
                        const float* __restrict__ cb2, const float* __restrict__ bout,
                        const uint32* __restrict__ ws, float* __restrict__ out) {
  __shared__ __align__(16) uint32 lds[4 * 48 * LROW];
  const int tid = threadIdx.x, lane = tid & 63, wv = tid >> 6;
  const int q = lane >> 4, nn = lane & 15;
  uint32* xnbuf = lds + wv * 48 * LROW;   // 32 rows (16 g8-groups x 2 cb)
  uint32* tbuf = xnbuf + 32 * LROW;       // 16 rows

  const uint4* A0  = (const uint4*)ws;
  const uint4* A23 = (const uint4*)(ws + 4096);
  const uint4* AP1 = (const uint4*)(ws + 16384);
  const uint4* AP2 = (const uint4*)(ws + 17408);
  const uint4* CW1 = (const uint4*)(ws + 19456);
  const uint4* WO  = (const uint4*)(ws + 23552);
  const uint4* CW2 = (const uint4*)(ws + 27648);

  // per-lane constants (hoisted out of the pair loop)
  const float b0A = b0[lane], b0B = b0[lane + 64];
  const float nb2r = -b2[lane], b3r = b3[lane], b1r = b1[lane];
  const float cb2A = cb2[lane], cb2B = cb2[lane + 64];
  const float boutA = bout[lane], boutB = bout[lane + 64];
  const uint4 cwc0 = CW2[lane * 2], cwc1 = CW2[lane * 2 + 1];

  // wave owns 16 CONSECUTIVE positions: one writer per 64B output line, XCD-local
  const int gwave = blockIdx.x * 4 + wv;
  const int pbase = gwave * 16;
  const int b = pbase >> 14;        // constant across the 16 positions
  const int nb = pbase & 16383;

  for (int pr = 0; pr < 8; ++pr) {
    const int n0 = nb + pr * 2;

    // ---- feats B-frags (cb, ks): B[k=c][n=kk] (streaming: nontemporal)
    bf16x8 bft[2][2];
#pragma unroll
    for (int cb = 0; cb < 2; cb++) {
      const float* fb = feats + (((size_t)b * 64) * 16384 + (n0 + cb)) * 16 + nn;
#pragma unroll
      for (int ks = 0; ks < 2; ks++) {
        float fv[8];
#pragma unroll
        for (int j = 0; j < 8; j++) {
          int c = ks * 32 + q * 8 + j;
          fv[j] = __builtin_nontemporal_load(fb + (size_t)c * 262144);
        }
        uint4 u;
        u.x = pack_bf16(fv[0], fv[1]); u.y = pack_bf16(fv[2], fv[3]);
        u.z = pack_bf16(fv[4], fv[5]); u.w = pack_bf16(fv[6], fv[7]);
        bft[cb][ks] = __builtin_bit_cast(bf16x8, u);
      }
    }
    // ---- GEMM1: xn = relu(w0@feats + b0); bias via shfl (no table read)
    floatx4 acc1[8][2];
#pragma unroll
    for (int rb = 0; rb < 8; rb++) {
      float src = (rb < 4) ? b0A : b0B;
      floatx4 bi;
#pragma unroll
      for (int r = 0; r < 4; r++) bi[r] = __shfl(src, (rb & 3) * 16 + q * 4 + r, 64);
      acc1[rb][0] = bi; acc1[rb][1] = bi;
    }
#pragma unroll
    for (int rb = 0; rb < 8; rb++)
#pragma unroll
      for (int ks = 0; ks < 2; ks++) {
        bf16x8 a = __builtin_bit_cast(bf16x8, A0[(rb * 2 + ks) * 64 + lane]);
        acc1[rb][0] = MFMA16(a, bft[0][ks], acc1[rb][0]);
        acc1[rb][1] = MFMA16(a, bft[1][ks], acc1[rb][1]);
      }
    // relu + store xn to LDS in B-frag layout
#pragma unroll
    for (int rb = 0; rb < 8; rb++)
#pragma unroll
      for (int cb = 0; cb < 2; cb++) {
        float v0 = fmaxf(acc1[rb][cb][0], 0.f), v1 = fmaxf(acc1[rb][cb][1], 0.f);
        float v2 = fmaxf(acc1[rb][cb][2], 0.f), v3 = fmaxf(acc1[rb][cb][3], 0.f);
        int g8 = 2 * rb + (q >> 1);
        int base = (g8 * 2 + cb) * LROW + nn * 4 + (q & 1) * 2;
        xnbuf[base] = pack_bf16(v0, v1); xnbuf[base + 1] = pack_bf16(v2, v3);
      }
    // ---- pw1: t = relu(pw1 @ ppfs)
    bf16x8 bpp[2];
#pragma unroll
    for (int cb = 0; cb < 2; cb++) {
      uint4 u;
      if (q == 0) {
        const float* pb = ppfs + (((size_t)b * 8) * 16384 + (n0 + cb)) * 16 + nn;
        float pv[8];
#pragma unroll
        for (int j = 0; j < 8; j++) pv[j] = __builtin_nontemporal_load(pb + (size_t)j * 262144);
        u.x = pack_bf16(pv[0], pv[1]); u.y = pack_bf16(pv[2], pv[3]);
        u.z = pack_bf16(pv[4], pv[5]); u.w = pack_bf16(pv[6], pv[7]);
      } else { u.x = 0u; u.y = 0u; u.z = 0u; u.w = 0u; }
      bpp[cb] = __builtin_bit_cast(bf16x8, u);
    }
    floatx4 acct[4][2];
#pragma unroll
    for (int rb = 0; rb < 4; rb++) {
      floatx4 z = {0.f, 0.f, 0.f, 0.f};
      acct[rb][0] = z; acct[rb][1] = z;
    }
#pragma unroll
    for (int rb = 0; rb < 4; rb++) {
      bf16x8 a = __builtin_bit_cast(bf16x8, AP1[rb * 64 + lane]);
      acct[rb][0] = MFMA16(a, bpp[0], acct[rb][0]);
      acct[rb][1] = MFMA16(a, bpp[1], acct[rb][1]);
    }
#pragma unroll
    for (int rb = 0; rb < 4; rb++)
#pragma unroll
      for (int cb = 0; cb < 2; cb++) {
        float v0 = fmaxf(acct[rb][cb][0], 0.f), v1 = fmaxf(acct[rb][cb][1], 0.f);
        float v2 = fmaxf(acct[rb][cb][2], 0.f), v3 = fmaxf(acct[rb][cb][3], 0.f);
        int g8 = 2 * rb + (q >> 1);
        int base = (g8 * 2 + cb) * LROW + nn * 4 + (q & 1) * 2;
        tbuf[base] = pack_bf16(v0, v1); tbuf[base + 1] = pack_bf16(v2, v3);
      }
    // ---- GEMM2 (rows 0-63: ptf-x2-b2, 64-127: x3+ptf+b3, 128-191: x1+b1)
    floatx4 acc2[12][2];
#pragma unroll
    for (int rb = 0; rb < 12; rb++) {
      float src = (rb < 4) ? nb2r : (rb < 8 ? b3r : b1r);
      floatx4 bi;
#pragma unroll
      for (int r = 0; r < 4; r++) bi[r] = __shfl(src, (rb & 3) * 16 + q * 4 + r, 64);
      acc2[rb][0] = bi; acc2[rb][1] = bi;
    }
#pragma unroll
    for (int ks = 0; ks < 2; ks++) {  // pw2 @ t  (K=64)
      bf16x8 bt0 = __builtin_bit_cast(bf16x8, *(const uint4*)(tbuf + ((ks * 4 + q) * 2 + 0) * LROW + nn * 4));
      bf16x8 bt1 = __builtin_bit_cast(bf16x8, *(const uint4*)(tbuf + ((ks * 4 + q) * 2 + 1) * LROW + nn * 4));
#pragma unroll
      for (int rbq = 0; rbq < 4; rbq++) {
        bf16x8 a = __builtin_bit_cast(bf16x8, AP2[(rbq * 2 + ks) * 64 + lane]);
        acc2[rbq][0] = MFMA16(a, bt0, acc2[rbq][0]);
        acc2[rbq][1] = MFMA16(a, bt1, acc2[rbq][1]);
        acc2[rbq + 4][0] = MFMA16(a, bt0, acc2[rbq + 4][0]);
        acc2[rbq + 4][1] = MFMA16(a, bt1, acc2[rbq + 4][1]);
      }
    }
#pragma unroll
    for (int ks = 0; ks < 4; ks++) {  // [-w2;w3;w1] @ xn  (K=128)
      bf16x8 bx0 = __builtin_bit_cast(bf16x8, *(const uint4*)(xnbuf + ((ks * 4 + q) * 2 + 0) * LROW + nn * 4));
      bf16x8 bx1 = __builtin_bit_cast(bf16x8, *(const uint4*)(xnbuf + ((ks * 4 + q) * 2 + 1) * LROW + nn * 4));
#pragma unroll
      for (int rb = 0; rb < 12; rb++) {
        bf16x8 a = __builtin_bit_cast(bf16x8, A23[(rb * 4 + ks) * 64 + lane]);
        acc2[rb][0] = MFMA16(a, bx0, acc2[rb][0]);
        acc2[rb][1] = MFMA16(a, bx1, acc2[rb][1]);
      }
    }
    // ---- epilogue, both positions together (shared table reads)
    // Phase F: h = relu(cw1 . xfs), xfs = x1 + (ptf - x2)
    float hp[2][8];
#pragma unroll
    for (int cb = 0; cb < 2; cb++)
#pragma unroll
      for (int j = 0; j < 8; j++) hp[cb][j] = 0.f;
#pragma unroll
    for (int rb = 0; rb < 4; rb++)
#pragma unroll
      for (int r = 0; r < 4; r++) {
        uint4 u = CW1[(rb * 4 + r) * 64 + lane];
#pragma unroll
        for (int cb = 0; cb < 2; cb++) {
          float xfs = __shfl(acc2[8 + rb][cb][r], lane & 0x30, 64) + acc2[rb][cb][r];
          hp[cb][0] = fmaf(bf_lo(u.x), xfs, hp[cb][0]); hp[cb][4] = fmaf(bf_hi(u.x), xfs, hp[cb][4]);
          hp[cb][1] = fmaf(bf_lo(u.y), xfs, hp[cb][1]); hp[cb][5] = fmaf(bf_hi(u.y), xfs, hp[cb][5]);
          hp[cb][2] = fmaf(bf_lo(u.z), xfs, hp[cb][2]); hp[cb][6] = fmaf(bf_hi(u.z), xfs, hp[cb][6]);
          hp[cb][3] = fmaf(bf_lo(u.w), xfs, hp[cb][3]); hp[cb][7] = fmaf(bf_hi(u.w), xfs, hp[cb][7]);
        }
      }
    float smv[2][2];     // [cb][A/B] softmax weights (per-lane)
    float om[2][4][4];   // [cb][rb][r]
#pragma unroll
    for (int cb = 0; cb < 2; cb++) {
      float h[8];
#pragma unroll
      for (int j = 0; j < 8; j++) {
        float v = hp[cb][j];
        v += __shfl_xor(v, 1, 64); v += __shfl_xor(v, 2, 64); v += __shfl_xor(v, 4, 64);
        v += __shfl_xor(v, 8, 64); v += __shfl_xor(v, 16, 64); v += __shfl_xor(v, 32, 64);
        h[j] = fmaxf(v, 0.f);
      }
      // Phase G: wl = cb2 + cw2 @ h (cwc0/cwc1 hoisted)
      float wlA = cb2A, wlB = cb2B;
      wlA = fmaf(bf_lo(cwc0.x), h[0], wlA); wlB = fmaf(bf_hi(cwc0.x), h[0], wlB);
      wlA = fmaf(bf_lo(cwc0.y), h[1], wlA); wlB = fmaf(bf_hi(cwc0.y), h[1], wlB);
      wlA = fmaf(bf_lo(cwc0.z), h[2], wlA); wlB = fmaf(bf_hi(cwc0.z), h[2], wlB);
      wlA = fmaf(bf_lo(cwc0.w), h[3], wlA); wlB = fmaf(bf_hi(cwc0.w), h[3], wlB);
      wlA = fmaf(bf_lo(cwc1.x), h[4], wlA); wlB = fmaf(bf_hi(cwc1.x), h[4], wlB);
      wlA = fmaf(bf_lo(cwc1.y), h[5], wlA); wlB = fmaf(bf_hi(cwc1.y), h[5], wlB);
      wlA = fmaf(bf_lo(cwc1.z), h[6], wlA); wlB = fmaf(bf_hi(cwc1.z), h[6], wlB);
      wlA = fmaf(bf_lo(cwc1.w), h[7], wlA); wlB = fmaf(bf_hi(cwc1.w), h[7], wlB);
      // Phase H: softmax over k within 16-lane groups
      float mA = wlA, mB = wlB;
#pragma unroll
      for (int s = 1; s < 16; s <<= 1) {
        mA = fmaxf(mA, __shfl_xor(mA, s, 64));
        mB = fmaxf(mB, __shfl_xor(mB, s, 64));
      }
      float eA = __expf(wlA - mA), eB = __expf(wlB - mB);
      float sA = eA, sB = eB;
#pragma unroll
      for (int s = 1; s < 16; s <<= 1) {
        sA += __shfl_xor(sA, s, 64);
        sB += __shfl_xor(sB, s, 64);
      }
      smv[cb][0] = eA / sA; smv[cb][1] = eB / sB;
      // Phase I: om[c] = relu(sum_k sm[c%8][k] * x3p[c][k])
      float sma[4], smb[4];
#pragma unroll
      for (int r = 0; r < 4; r++) {
        int src = r * 16 + nn;
        sma[r] = __shfl(smv[cb][0], src, 64);
        smb[r] = __shfl(smv[cb][1], src, 64);
      }
      const bool qodd = (q & 1);
#pragma unroll
      for (int rb = 0; rb < 4; rb++)
#pragma unroll
        for (int r = 0; r < 4; r++) {
          float sv = qodd ? smb[r] : sma[r];
          float v = sv * acc2[4 + rb][cb][r];
          v += __shfl_xor(v, 1, 64); v += __shfl_xor(v, 2, 64);
          v += __shfl_xor(v, 4, 64); v += __shfl_xor(v, 8, 64);
          om[cb][rb][r] = fmaxf(v, 0.f);
        }
    }
    // Phase J: out = wout @ om + bout + identity (WO frags shared across cb)
    float outA[2], outB[2];
    outA[0] = boutA; outA[1] = boutA; outB[0] = boutB; outB[1] = boutB;
#pragma unroll
    for (int cg = 0; cg < 16; cg++) {
      uint4 u = WO[cg * 64 + lane];
      int rb = cg >> 2, qq = (cg & 3) * 16;
#pragma unroll
      for (int cb = 0; cb < 2; cb++) {
        float s0 = bcast(om[cb][rb][0], qq), s1 = bcast(om[cb][rb][1], qq);
        float s2 = bcast(om[cb][rb][2], qq), s3 = bcast(om[cb][rb][3], qq);
        outA[cb] = fmaf(bf_lo(u.x), s0, outA[cb]); outB[cb] = fmaf(bf_hi(u.x), s0, outB[cb]);
        outA[cb] = fmaf(bf_lo(u.y), s1, outA[cb]); outB[cb] = fmaf(bf_hi(u.y), s1, outB[cb]);
        outA[cb] = fmaf(bf_lo(u.z), s2, outA[cb]); outB[cb] = fmaf(bf_hi(u.z), s2, outB[cb]);
        outA[cb] = fmaf(bf_lo(u.w), s3, outA[cb]); outB[cb] = fmaf(bf_hi(u.w), s3, outB[cb]);
      }
    }
    // identity (xn col 0, bf16 from LDS)
#pragma unroll
    for (int cb = 0; cb < 2; cb++) {
      int g8a = lane >> 3, wo = (lane & 7) >> 1;
      uint32 ia = xnbuf[(g8a * 2 + cb) * LROW + wo];
      uint32 ib = xnbuf[((8 + g8a) * 2 + cb) * LROW + wo];
      outA[cb] += (lane & 1) ? bf_hi(ia) : bf_lo(ia);
      outB[cb] += (lane & 1) ? bf_hi(ib) : bf_lo(ib);
    }
    // coalesced-ish paired store: 8B per lane, full 64B line per wave over 8 pairs
    {
      float2 oa, ob;
      oa.x = outA[0]; oa.y = outA[1]; ob.x = outB[0]; ob.y = outB[1];
      *(float2*)(out + ((size_t)(b * 128 + lane)) * 16384 + n0) = oa;
      *(float2*)(out + ((size_t)(b * 128 + lane + 64)) * 16384 + n0) = ob;
    }
  }
}

extern "C" void kernel_launch(void* const* d_in, const int* in_sizes, int n_in,
                              void* d_out, int out_size, void* d_ws, size_t ws_size,
                              hipStream_t stream) {
  const float* feats = (const float*)d_in[0];
  const float* ppfs = (const float*)d_in[1];
  const float* w0 = (const float*)d_in[2];
  const float* b0 = (const float*)d_in[3];
  const float* w1 = (const float*)d_in[4];
  const float* b1 = (const float*)d_in[5];
  const float* w2 = (const float*)d_in[6];
  const float* b2 = (const float*)d_in[7];
  const float* w3 = (const float*)d_in[8];
  const float* b3 = (const float*)d_in[9];
  const float* pw1 = (const float*)d_in[10];
  const float* pw2 = (const float*)d_in[11];
  const float* cw1 = (const float*)d_in[12];
  const float* cw2 = (const float*)d_in[13];
  const float* cb2 = (const float*)d_in[14];
  const float* wout = (const float*)d_in[15];
  const float* bout = (const float*)d_in[16];
  (void)in_sizes; (void)n_in; (void)out_size; (void)ws_size;

  uint32* ws = (uint32*)d_ws;
  hipLaunchKernelGGL(pack_w, dim3(32), dim3(256), 0, stream,
                     w0, w1, w2, w3, pw1, pw2, cw1, cw2, wout, ws);
  hipLaunchKernelGGL(pt_mfma, dim3(1024), dim3(256), 0, stream,
                     feats, ppfs, b0, b1, b2, b3, cb2, bout, ws, (float*)d_out);
}